// Round 3
// baseline (17201.405 us; speedup 1.0000x reference)
//
#include <hip/hip_runtime.h>
#include <math.h>

// Discriminator GRU: B=64, T=1024, S=1024.
// Round 4: persistent cooperative recurrence with a FENCE-FREE grid barrier.
//   - h exchanged via relaxed-AGENT-scope atomics (sc1): write-through/
//     read-through at L3, the cross-XCD coherence point. No wbL2/inv anywhere.
//   - W_hh / xgT read with plain loads -> stay cached in L2 across ALL steps
//     (L2 is never invalidated; W leaves L3 once, not 12 MB/step).
//   - Barrier: monotonic counters, 8 padded sub-counters -> 1 top counter,
//     RELAXED spin polls (round-2's 38 us/step came from ACQUIRE spin invs +
//     per-block __threadfence wbL2+inv).
//   K1: xgT[t][g][u][b] GEMM (transposed out) unchanged.
//   K3: out[b] = sigmoid(h_T[b] . W_out + b_out) unchanged.
// ws layout: [ xgT: 64*1024*3072 f32 (768 MB) | hA: 1024*64 f32 | hB: 1024*64 ]

#define BB 64
#define TT 1024
#define SS 1024
#define GG (3 * SS)
#define NBLK 256

// Barrier state in device globals (ws is poisoned each launch). Monotonic
// counters, re-zeroed every replay by init_bar_kernel. 128B padding per line.
__device__ unsigned g_sub[8 * 32];  // 8 sub-counters, one cacheline apart
__device__ unsigned g_cnt[32];      // top-level counter
__device__ unsigned g_gen[32];      // generation (published step count)

__global__ void init_bar_kernel() {
  for (int i = 0; i < 8 * 32; ++i) g_sub[i] = 0u;
  g_cnt[0] = 0u;
  g_gen[0] = 0u;
}

__global__ void zero_kernel(float* __restrict__ p) {
  p[(size_t)blockIdx.x * 1024 + threadIdx.x] = 0.f;
}

// ---------------------------------------------------------------------------
// K1: C layout = xgT[((t*3+g)*S + u)*64 + b].
// 128x128 tile, BK=16, 256 threads, 8x8 microtile. m-tile = 2 timesteps x 64
// batches so the transposed epilogue stores stay 64B-line coalesced.
// ---------------------------------------------------------------------------
__global__ __launch_bounds__(256) void xgates_kernel(
    const float* __restrict__ A, const float* __restrict__ W,
    const float* __restrict__ b_ih, const float* __restrict__ b_hh,
    float* __restrict__ C) {
  __shared__ float As[16][132];  // [k][m], +4 pad
  __shared__ float Bs[16][132];  // [k][n]

  const int tid = threadIdx.x;
  const int n0 = blockIdx.x * 128;  // 24 n-tiles
  const int t0 = blockIdx.y * 2;    // 512 m-tiles; tile = 2 t x 64 b
  const int tx = tid & 15;          // n dir
  const int ty = tid >> 4;          // m dir

  float acc[8][8];
#pragma unroll
  for (int i = 0; i < 8; ++i)
#pragma unroll
    for (int j = 0; j < 8; ++j) acc[i][j] = 0.f;

  for (int kt = 0; kt < SS / 16; ++kt) {
    const int k0 = kt * 16;
#pragma unroll
    for (int i = 0; i < 2; ++i) {
      const int idx = tid + i * 256;  // 0..511
      const int r = idx >> 2;         // tile row 0..127: b = r&63, t = t0+(r>>6)
      const int kq = (idx & 3) * 4;
      float4 av = *(const float4*)&A[((size_t)(r & 63) * TT + t0 + (r >> 6)) * SS + k0 + kq];
      float4 bv = *(const float4*)&W[(size_t)(n0 + r) * SS + k0 + kq];
      As[kq + 0][r] = av.x; As[kq + 1][r] = av.y;
      As[kq + 2][r] = av.z; As[kq + 3][r] = av.w;
      Bs[kq + 0][r] = bv.x; Bs[kq + 1][r] = bv.y;
      Bs[kq + 2][r] = bv.z; Bs[kq + 3][r] = bv.w;
    }
    __syncthreads();
#pragma unroll
    for (int k = 0; k < 16; ++k) {
      float4 a0 = *(const float4*)&As[k][ty * 8];
      float4 a1 = *(const float4*)&As[k][ty * 8 + 4];
      float4 b0 = *(const float4*)&Bs[k][tx * 8];
      float4 b1 = *(const float4*)&Bs[k][tx * 8 + 4];
      float a[8] = {a0.x, a0.y, a0.z, a0.w, a1.x, a1.y, a1.z, a1.w};
      float b[8] = {b0.x, b0.y, b0.z, b0.w, b1.x, b1.y, b1.z, b1.w};
#pragma unroll
      for (int i = 0; i < 8; ++i)
#pragma unroll
        for (int j = 0; j < 8; ++j) acc[i][j] = fmaf(a[i], b[j], acc[i][j]);
    }
    __syncthreads();
  }

  float bias[8];
#pragma unroll
  for (int j = 0; j < 8; ++j) {
    const int n = n0 + tx * 8 + j;
    bias[j] = b_ih[n] + (n < 2 * SS ? b_hh[n] : 0.f);
  }
  // row ty*8+i -> b = (ty&7)*8 + i, t = t0 + (ty>>3)
  const int tt = t0 + (ty >> 3);
  const int bbase = (ty & 7) * 8;
#pragma unroll
  for (int j = 0; j < 8; ++j) {
    const int n = n0 + tx * 8 + j;
    const int g = n >> 10;
    const int u = n & 1023;
    const size_t o = ((size_t)(tt * 3 + g) * SS + u) * 64 + bbase;
    *(float4*)&C[o] = make_float4(acc[0][j] + bias[j], acc[1][j] + bias[j],
                                  acc[2][j] + bias[j], acc[3][j] + bias[j]);
    *(float4*)&C[o + 4] = make_float4(acc[4][j] + bias[j], acc[5][j] + bias[j],
                                      acc[6][j] + bias[j], acc[7][j] + bias[j]);
  }
}

// ---------------------------------------------------------------------------
// K2: persistent GRU recurrence. 256 blocks x 1024 threads (16 waves = 4
// waves/SIMD on all 256 CUs). Block owns units u0..u0+3 (12 gate-rows);
// wave wv owns k-slice [wv*64, wv*64+64); lane = batch.
//   - hin loads / hout stores: relaxed-agent atomics (sc1 -> L3-coherent).
//   - W via wave-uniform plain loads (s_load broadcast, L2-resident all steps).
//   - 16-way k-split reduced through LDS (stride 13, conflict-free).
//   - Grid barrier per step (skipped after the last step): monotonic
//     sub-counter -> top-counter cascade, relaxed sc1 spin + s_sleep.
// ---------------------------------------------------------------------------
__global__ __launch_bounds__(1024) void gru_persistent(
    const float* __restrict__ Whh, const float* __restrict__ xgT,
    const float* __restrict__ bhh, float* hA, float* hB) {
  __shared__ float part[16][64][13];  // [wave][b][g*4+r]  53.2 KB
  __shared__ float sums[64][13];      //                    3.3 KB

  const int tid = threadIdx.x;
  const int lane = tid & 63;  // batch
  const int u0 = blockIdx.x * 4;
  const int wv = __builtin_amdgcn_readfirstlane(tid >> 6);  // uniform 0..15
  const int k0 = wv * 64;
  const int ur = tid >> 6;  // gate-phase unit (valid when tid < 256)

  const float* Wrow[12];  // uniform row bases -> SGPRs
#pragma unroll
  for (int g = 0; g < 3; ++g)
#pragma unroll
    for (int r = 0; r < 4; ++r)
      Wrow[g * 4 + r] = Whh + (size_t)(g * SS + u0 + r) * SS + k0;

  float bhn = 0.f, xr = 0.f, xz = 0.f, xn = 0.f;
  if (tid < 256) {
    bhn = bhh[2 * SS + u0 + ur];
    // x-gate prefetch for t=0
    const size_t xb = (size_t)(u0 + ur) * 64 + (size_t)lane;
    xr = xgT[xb];
    xz = xgT[xb + (size_t)SS * 64];
    xn = xgT[xb + (size_t)2 * SS * 64];
  }

  for (int t = 0; t < TT; ++t) {
    float* hin = (t & 1) ? hB : hA;
    float* hout = (t & 1) ? hA : hB;

    float hold = 0.f;
    if (tid < 256)
      hold = __hip_atomic_load(&hin[(u0 + ur) * 64 + lane], __ATOMIC_RELAXED,
                               __HIP_MEMORY_SCOPE_AGENT);

    float acc[12];
#pragma unroll
    for (int i = 0; i < 12; ++i) acc[i] = 0.f;

    for (int kk = 0; kk < 64; kk += 8) {
      float hv[8];
#pragma unroll
      for (int e = 0; e < 8; ++e)
        hv[e] = __hip_atomic_load(&hin[(size_t)(k0 + kk + e) * 64 + lane],
                                  __ATOMIC_RELAXED, __HIP_MEMORY_SCOPE_AGENT);
#pragma unroll
      for (int i = 0; i < 12; ++i) {
        const float* wp = Wrow[i] + kk;
        const float4 wa = *(const float4*)wp;
        const float4 wb = *(const float4*)(wp + 4);
        float a = acc[i];
        a = fmaf(hv[0], wa.x, a);
        a = fmaf(hv[1], wa.y, a);
        a = fmaf(hv[2], wa.z, a);
        a = fmaf(hv[3], wa.w, a);
        a = fmaf(hv[4], wb.x, a);
        a = fmaf(hv[5], wb.y, a);
        a = fmaf(hv[6], wb.z, a);
        a = fmaf(hv[7], wb.w, a);
        acc[i] = a;
      }
    }

    const int w = tid >> 6;
#pragma unroll
    for (int i = 0; i < 12; ++i) part[w][lane][i] = acc[i];
    __syncthreads();

    // Reduce 16 k-split partials: 768 sums, threads 0..767 (one each).
    if (tid < 768) {
      const int sb = tid & 63, si = tid >> 6;  // si 0..11
      float v = 0.f;
#pragma unroll
      for (int ww = 0; ww < 16; ++ww) v += part[ww][sb][si];
      sums[sb][si] = v;
    }
    __syncthreads();

    // Gate math + h update: 256 threads = 64 b x 4 units.
    if (tid < 256) {
      const float ar = sums[lane][ur];
      const float az = sums[lane][4 + ur];
      const float an = sums[lane][8 + ur];
      const float rg = 1.f / (1.f + expf(-(xr + ar)));
      const float zg = 1.f / (1.f + expf(-(xz + az)));
      const float ng = tanhf(xn + rg * (an + bhn));
      const float hnew = (1.f - zg) * ng + zg * hold;
      __hip_atomic_store(&hout[(u0 + ur) * 64 + lane], hnew, __ATOMIC_RELAXED,
                         __HIP_MEMORY_SCOPE_AGENT);
      // Prefetch next step's x-gates; latency hides under the barrier.
      if (t + 1 < TT) {
        const size_t xb =
            ((size_t)((t + 1) * 3) * SS + u0 + ur) * 64 + (size_t)lane;
        xr = xgT[xb];
        xz = xgT[xb + (size_t)SS * 64];
        xn = xgT[xb + (size_t)2 * SS * 64];
      }
    }

    if (t != TT - 1) {
      // Grid barrier. __syncthreads' per-wave vmcnt drain guarantees every
      // wave's sc1 h-stores have been acked by L3 before the arrival atomic.
      __syncthreads();
      if (tid == 0) {
        bool done = false;
        const unsigned a = atomicAdd(&g_sub[(blockIdx.x & 7) * 32], 1u);
        if (a == 32u * (unsigned)(t + 1) - 1u) {  // last of my 32-block group
          const unsigned g = atomicAdd(&g_cnt[0], 1u);
          if (g == 8u * (unsigned)(t + 1) - 1u) {  // last group overall
            __hip_atomic_store(&g_gen[0], (unsigned)(t + 1), __ATOMIC_RELAXED,
                               __HIP_MEMORY_SCOPE_AGENT);
            done = true;
          }
        }
        if (!done) {
          while (__hip_atomic_load(&g_gen[0], __ATOMIC_RELAXED,
                                   __HIP_MEMORY_SCOPE_AGENT) <
                 (unsigned)(t + 1))
            __builtin_amdgcn_s_sleep(2);
        }
        __builtin_amdgcn_fence(__ATOMIC_ACQUIRE, "workgroup");  // compile bar
      }
      __syncthreads();
    }
  }
}

// ---------------------------------------------------------------------------
// K3: out[b] = sigmoid(h[b] . W_out + b_out). h is transposed: hT[u][b].
// ---------------------------------------------------------------------------
__global__ __launch_bounds__(256) void out_kernel(
    const float* __restrict__ hT, const float* __restrict__ Wout,
    const float* __restrict__ bout, float* __restrict__ out) {
  const int b = blockIdx.x;
  const int tid = threadIdx.x;
  float s = 0.f;
#pragma unroll
  for (int i = 0; i < 4; ++i) {
    const int u = tid + i * 256;
    s = fmaf(hT[(size_t)u * 64 + b], Wout[u], s);
  }
#pragma unroll
  for (int off = 32; off; off >>= 1) s += __shfl_down(s, off);
  __shared__ float red[4];
  if ((tid & 63) == 0) red[tid >> 6] = s;
  __syncthreads();
  if (tid == 0) {
    const float tot = red[0] + red[1] + red[2] + red[3] + bout[0];
    out[b] = 1.f / (1.f + expf(-tot));
  }
}

// ---------------------------------------------------------------------------
extern "C" void kernel_launch(void* const* d_in, const int* in_sizes, int n_in,
                              void* d_out, int out_size, void* d_ws,
                              size_t ws_size, hipStream_t stream) {
  const float* batch = (const float*)d_in[0];  // [B,T,S]
  const float* W_ih = (const float*)d_in[1];   // [3S,S]
  const float* W_hh = (const float*)d_in[2];   // [3S,S]
  const float* b_ih = (const float*)d_in[3];   // [3S]
  const float* b_hh = (const float*)d_in[4];   // [3S]
  const float* W_out = (const float*)d_in[5];  // [1,S]
  const float* b_out = (const float*)d_in[6];  // [1]
  float* out = (float*)d_out;                  // [B]

  float* xgT = (float*)d_ws;               // [T][3][S][B] f32 (768 MB)
  float* hA = xgT + (size_t)TT * GG * BB;  // hT [S][B]
  float* hB = hA + (size_t)SS * BB;

  init_bar_kernel<<<1, 1, 0, stream>>>();
  zero_kernel<<<BB, 1024, 0, stream>>>(hA);  // h0 = 0 (1024*64 floats)

  xgates_kernel<<<dim3(GG / 128, (BB * TT) / 128), 256, 0, stream>>>(
      batch, W_ih, b_ih, b_hh, xgT);

  // Persistent recurrence: cooperative launch guarantees co-residency of all
  // 256 blocks (1 block/CU; LDS 56.5 KB, 16 waves).
  {
    const float* a0 = W_hh;
    const float* a1 = xgT;
    const float* a2 = b_hh;
    float* a3 = hA;
    float* a4 = hB;
    void* args[5] = {&a0, &a1, &a2, &a3, &a4};
    hipLaunchCooperativeKernel((const void*)gru_persistent, dim3(NBLK),
                               dim3(1024), args, 0, stream);
  }
  // t=1023 (odd) writes hA -> final h in hA

  out_kernel<<<BB, 256, 0, stream>>>(hA, W_out, b_out, out);
}